// Round 6
// baseline (230.148 us; speedup 1.0000x reference)
//
#include <hip/hip_runtime.h>

// LIF scan, T=8, N=4M fp32. 256 MiB logical traffic, roofline ~43 us @ 6.3 TB/s.
// R1-R4: all structures plateaued at 2.1-2.4 TB/s -> cache-allocate path cap.
// R5: nontemporal loads broke the cap (kernel dropped below the harness's 80 us
// fill dispatches; fills themselves sustain 6.7 TB/s = proof of headroom).
// R6: nt loads + asm-forced 8-deep load batch (un-sinkable, single waitcnt,
// stores strictly after loads) to stack per-wave MLP on top of the nt policy.

#define LIF_THRESH 0.5f
#define LIF_BETA   0.25f
#define LIF_T      8

typedef float v4f __attribute__((ext_vector_type(4)));

__device__ __forceinline__ float lif_step(float& m, float xv) {
    m = m * LIF_BETA + xv;
    float s = (m >= LIF_THRESH) ? 1.f : 0.f;
    m = (m >= LIF_THRESH) ? 0.f : m;
    return s;
}

__global__ __launch_bounds__(256) void lif_kernel(const v4f* __restrict__ x,
                                                  v4f* __restrict__ out,
                                                  int n4) {
    int i = blockIdx.x * 256 + threadIdx.x;
    if (i >= n4) return;

    const v4f* p0 = x + i;
    const v4f* p1 = p0 + (size_t)n4;
    const v4f* p2 = p1 + (size_t)n4;
    const v4f* p3 = p2 + (size_t)n4;
    const v4f* p4 = p3 + (size_t)n4;
    const v4f* p5 = p4 + (size_t)n4;
    const v4f* p6 = p5 + (size_t)n4;
    const v4f* p7 = p6 + (size_t)n4;

    // 8 nontemporal loads issued back-to-back; volatile asm is mutually ordered
    // and cannot be sunk. 8 KiB outstanding per wave + streaming cache policy.
    v4f x0, x1, x2, x3, x4, x5, x6, x7;
    asm volatile("global_load_dwordx4 %0, %1, off nt" : "=v"(x0) : "v"(p0) : "memory");
    asm volatile("global_load_dwordx4 %0, %1, off nt" : "=v"(x1) : "v"(p1) : "memory");
    asm volatile("global_load_dwordx4 %0, %1, off nt" : "=v"(x2) : "v"(p2) : "memory");
    asm volatile("global_load_dwordx4 %0, %1, off nt" : "=v"(x3) : "v"(p3) : "memory");
    asm volatile("global_load_dwordx4 %0, %1, off nt" : "=v"(x4) : "v"(p4) : "memory");
    asm volatile("global_load_dwordx4 %0, %1, off nt" : "=v"(x5) : "v"(p5) : "memory");
    asm volatile("global_load_dwordx4 %0, %1, off nt" : "=v"(x6) : "v"(p6) : "memory");
    asm volatile("global_load_dwordx4 %0, %1, off nt" : "=v"(x7) : "v"(p7) : "memory");
    // Single drain; "+v" ties every result so no consumer can move above it.
    asm volatile("s_waitcnt vmcnt(0)"
                 : "+v"(x0), "+v"(x1), "+v"(x2), "+v"(x3),
                   "+v"(x4), "+v"(x5), "+v"(x6), "+v"(x7)
                 :
                 : "memory");

    float m0 = 0.f, m1 = 0.f, m2 = 0.f, m3 = 0.f;
    v4f s0, s1, s2, s3, s4, s5, s6, s7;
#define STEP(S, XV)                    \
    S.x = lif_step(m0, XV.x);          \
    S.y = lif_step(m1, XV.y);          \
    S.z = lif_step(m2, XV.z);          \
    S.w = lif_step(m3, XV.w);
    STEP(s0, x0) STEP(s1, x1) STEP(s2, x2) STEP(s3, x3)
    STEP(s4, x4) STEP(s5, x5) STEP(s6, x6) STEP(s7, x7)
#undef STEP

    // All stores after all loads; nt policy (write-once output).
    v4f* q = out + i;
    __builtin_nontemporal_store(s0, q); q += n4;
    __builtin_nontemporal_store(s1, q); q += n4;
    __builtin_nontemporal_store(s2, q); q += n4;
    __builtin_nontemporal_store(s3, q); q += n4;
    __builtin_nontemporal_store(s4, q); q += n4;
    __builtin_nontemporal_store(s5, q); q += n4;
    __builtin_nontemporal_store(s6, q); q += n4;
    __builtin_nontemporal_store(s7, q);
}

extern "C" void kernel_launch(void* const* d_in, const int* in_sizes, int n_in,
                              void* d_out, int out_size, void* d_ws, size_t ws_size,
                              hipStream_t stream) {
    const v4f* x = (const v4f*)d_in[0];
    v4f* out = (v4f*)d_out;

    long long total = in_sizes[0];
    int n = (int)(total / LIF_T);   // 4,194,304 floats per timestep
    int n4 = n / 4;                 // 1,048,576 float4 per timestep

    dim3 block(256);
    dim3 grid((n4 + 255) / 256);    // 4096 blocks
    lif_kernel<<<grid, block, 0, stream>>>(x, out, n4);
}